// Round 21
// baseline (281.164 us; speedup 1.0000x reference)
//
#include <hip/hip_runtime.h>

typedef __attribute__((ext_vector_type(8))) __bf16 bf16x8;
typedef __attribute__((ext_vector_type(4))) float f32x4;

#define IMG 112
#define SHF 3

__device__ __forceinline__ ushort f2bf(float f) {
  return __builtin_bit_cast(unsigned short, static_cast<__bf16>(f));
}
__device__ __forceinline__ uint pk2(float lo, float hi) {
  return (uint)f2bf(lo) | ((uint)f2bf(hi) << 16);
}
__device__ __forceinline__ int d7(int n) { return (n * 9363) >> 16; }  // n/7 for n<=63

// Full-K=32 packing of two D-frags (verified R16): k' = 8*kg + j;
// j=0..3 <- d0 rows (kg*4+i), j=4..7 <- d1 rows (16+kg*4+i).
__device__ __forceinline__ bf16x8 pack2(const f32x4 d0, const f32x4 d1) {
  union { uint4 u; bf16x8 v; } r;
  r.u = uint4{ pk2(d0[0], d0[1]), pk2(d0[2], d0[3]),
               pk2(d1[0], d1[1]), pk2(d1[2], d1[3]) };
  return r.v;
}
__device__ __forceinline__ bf16x8 pack2b(const f32x4 d0, const float4 b0,
                                         const f32x4 d1, const float4 b1) {
  union { uint4 u; bf16x8 v; } r;
  r.u = uint4{ pk2(d0[0] + b0.x, d0[1] + b0.y), pk2(d0[2] + b0.z, d0[3] + b0.w),
               pk2(d1[0] + b1.x, d1[1] + b1.y), pk2(d1[2] + b1.z, d1[3] + b1.w) };
  return r.v;
}

// ---------------- prep: bf16 weights (+q scale*log2e fold), biases, log2e-scaled rpb+mask ----
// wRM[cls][h][64 qt][64 kt] = log2e*(rpb + masks); softmax exp done as exp2.
__global__ void prep_kernel(const float* __restrict__ Wq, const float* __restrict__ Wk,
                            const float* __restrict__ Wv, const float* __restrict__ Wp,
                            const float* __restrict__ bq, const float* __restrict__ bk,
                            const float* __restrict__ bv, const float* __restrict__ bp,
                            const float* __restrict__ tbl,
                            ushort* __restrict__ wW, float* __restrict__ wB,
                            float* __restrict__ wRM) {
  int t = blockIdx.x * 256 + threadIdx.x;
  const float LOG2E = 1.4426950408889634f;
  const float SC = 0.17677669529663687f * LOG2E;  // 32^-0.5 * log2(e)
  if (t < 65536) {
    int m = t >> 14, e = t & 16383;
    const float* W = (m == 0) ? Wq : (m == 1) ? Wk : (m == 2) ? Wv : Wp;
    float v = W[e];
    if (m == 0) v *= SC;
    wW[t] = f2bf(v);
  } else if (t < 66048) {
    int t2 = t - 65536;
    int m = t2 >> 7, e = t2 & 127;
    const float* B = (m == 0) ? bq : (m == 1) ? bk : (m == 2) ? bv : bp;
    float v = B[e];
    if (m == 0) v *= SC;
    wB[t2] = v;
  } else if (t < 131584) {
    int t3 = t - 66048;  // [0, 65536)
    int cls = t3 >> 14;
    int r = t3 & 16383;
    int h = r >> 12;
    int rr = r & 4095;
    int qt = rr >> 6, kt = rr & 63;
    float v;
    if (qt >= 49) v = 0.0f;
    else if (kt >= 49) v = -1e30f;
    else {
      int rq = qt / 7, cq = qt % 7, rk = kt / 7, ck = kt % 7;
      v = tbl[((rq - rk + 6) * 13 + (cq - ck + 6)) * 4 + h];
      int eH = (cls >> 1) & 1, eW = cls & 1;
      int ridq = (eH ? (rq < 4 ? 3 : 6) : 0) + (eW ? (cq < 4 ? 1 : 2) : 0);
      int ridk = (eH ? (rk < 4 ? 3 : 6) : 0) + (eW ? (ck < 4 ? 1 : 2) : 0);
      if (ridq != ridk) v -= 100.0f;
    }
    wRM[t3] = v * LOG2E;
  }
}

// LDS (ushort units): x_s [0, 6664) = [49][136];  o_s [6664, 13328) = [49][136].
#define OS 6664

// Block = 256 threads = 4 waves; wave wv = head h, end-to-end in registers.
// Full per-bt fusion: S -> softmax(exp2) -> pack -> PV -> reduce -> o_s write, per column.
// Peak live ~105 regs -> 4 waves/SIMD (128-reg unified budget).
__global__ __launch_bounds__(256, 4) void swin_kernel(
    const float* __restrict__ X, const ushort* __restrict__ wW,
    const float* __restrict__ wB, const float* __restrict__ wRM,
    float* __restrict__ out) {
  __shared__ ushort lds[13328];
  const int tid = threadIdx.x;
  const int wv = tid >> 6;  // 0..3 = head
  const int lane = tid & 63;
  const int lr = lane & 15;
  const int kg = lane >> 4;

  const int blk = blockIdx.x;
  const int b = blk >> 8;
  const int wid = blk & 255;
  const int wi = wid >> 4, wj = wid & 15;
  const size_t gBase = (size_t)b * (IMG * IMG * 128);
  const int h = wv;
  const int r3 = 48 + lr;

  // ---------------- Phase A: gather rolled window (hoisted chains) ----------------
  {
    float4 va[7]; int rowa[7], q4a[7]; bool ok[7];
#pragma unroll
    for (int i = 0; i < 7; ++i) {
      int idx = tid + i * 256;
      ok[i] = idx < 49 * 32;
      int row = idx >> 5, q4 = idx & 31;
      rowa[i] = row; q4a[i] = q4;
      if (ok[i]) {
        int r = d7(row), c = row - r * 7;
        int gh = wi * 7 + r + SHF; if (gh >= IMG) gh -= IMG;
        int gw = wj * 7 + c + SHF; if (gw >= IMG) gw -= IMG;
        va[i] = reinterpret_cast<const float4*>(X + gBase + ((size_t)gh * IMG + gw) * 128)[q4];
      }
    }
#pragma unroll
    for (int i = 0; i < 7; ++i) {
      if (ok[i]) {
        ushort4 h4 = { f2bf(va[i].x), f2bf(va[i].y), f2bf(va[i].z), f2bf(va[i].w) };
        *reinterpret_cast<ushort4*>(&lds[rowa[i] * 136 + q4a[i] * 4]) = h4;
      }
    }
  }
  __syncthreads();  // barrier 1

  // x-fragment loader (LDS, per-kk, per-tile; tt<3 rows never exceed 47)
  auto ldx = [&](int tt, int kk) -> bf16x8 {
    int row = (tt < 3) ? (tt * 16 + lr) : ((r3 > 48) ? 48 : r3);
    return *reinterpret_cast<const bf16x8*>(&lds[row * 136 + kk * 32 + kg * 8]);
  };

  // ---------------- K projection: D[ch][tok] -> full-K packed A-frags kfp[tt] ----------------
  bf16x8 kfp[4];
  {
    f32x4 acc[2][4] = {};
#pragma unroll
    for (int kk = 0; kk < 4; ++kk) {
      bf16x8 w0 = *reinterpret_cast<const bf16x8*>(&wW[16384 + (h * 32 + lr) * 128 + kk * 32 + kg * 8]);
      bf16x8 w1 = *reinterpret_cast<const bf16x8*>(&wW[16384 + (h * 32 + 16 + lr) * 128 + kk * 32 + kg * 8]);
#pragma unroll
      for (int tt = 0; tt < 4; ++tt) {
        bf16x8 x = ldx(tt, kk);
        acc[0][tt] = __builtin_amdgcn_mfma_f32_16x16x32_bf16(w0, x, acc[0][tt], 0, 0, 0);
        acc[1][tt] = __builtin_amdgcn_mfma_f32_16x16x32_bf16(w1, x, acc[1][tt], 0, 0, 0);
      }
    }
    float4 b0 = *reinterpret_cast<const float4*>(&wB[128 + h * 32 + kg * 4]);
    float4 b1 = *reinterpret_cast<const float4*>(&wB[128 + h * 32 + 16 + kg * 4]);
#pragma unroll
    for (int tt = 0; tt < 4; ++tt)
      kfp[tt] = pack2b(acc[0][tt], b0, acc[1][tt], b1);
  }

  // ---------------- V projection: D[tok][ch] -> full-K packed A-frags vfp[c][nt] ----------------
  bf16x8 vfp[2][2];  // [c tok-pair][nt d-tile]
  {
    f32x4 acc[4][2] = {};
#pragma unroll
    for (int kk = 0; kk < 4; ++kk) {
      bf16x8 w0 = *reinterpret_cast<const bf16x8*>(&wW[32768 + (h * 32 + lr) * 128 + kk * 32 + kg * 8]);
      bf16x8 w1 = *reinterpret_cast<const bf16x8*>(&wW[32768 + (h * 32 + 16 + lr) * 128 + kk * 32 + kg * 8]);
#pragma unroll
      for (int tt = 0; tt < 4; ++tt) {
        bf16x8 x = ldx(tt, kk);
        acc[tt][0] = __builtin_amdgcn_mfma_f32_16x16x32_bf16(x, w0, acc[tt][0], 0, 0, 0);
        acc[tt][1] = __builtin_amdgcn_mfma_f32_16x16x32_bf16(x, w1, acc[tt][1], 0, 0, 0);
      }
    }
    float bv0 = wB[256 + h * 32 + lr];
    float bv1 = wB[256 + h * 32 + 16 + lr];
#pragma unroll
    for (int c = 0; c < 2; ++c) {
      f32x4 t00 = acc[2 * c][0], t10 = acc[2 * c + 1][0];
      f32x4 t01 = acc[2 * c][1], t11 = acc[2 * c + 1][1];
#pragma unroll
      for (int i = 0; i < 4; ++i) { t00[i] += bv0; t10[i] += bv0; t01[i] += bv1; t11[i] += bv1; }
      vfp[c][0] = pack2(t00, t10);
      vfp[c][1] = pack2(t01, t11);
    }
  }

  // ---------------- Q projection: D[ch][qt] -> full-K packed B-frags qpp[bt] ----------------
  bf16x8 qpp[4];
  {
    f32x4 acc[2][4] = {};
#pragma unroll
    for (int kk = 0; kk < 4; ++kk) {
      bf16x8 w0 = *reinterpret_cast<const bf16x8*>(&wW[(h * 32 + lr) * 128 + kk * 32 + kg * 8]);
      bf16x8 w1 = *reinterpret_cast<const bf16x8*>(&wW[(h * 32 + 16 + lr) * 128 + kk * 32 + kg * 8]);
#pragma unroll
      for (int bt = 0; bt < 4; ++bt) {
        bf16x8 x = ldx(bt, kk);
        acc[0][bt] = __builtin_amdgcn_mfma_f32_16x16x32_bf16(w0, x, acc[0][bt], 0, 0, 0);
        acc[1][bt] = __builtin_amdgcn_mfma_f32_16x16x32_bf16(w1, x, acc[1][bt], 0, 0, 0);
      }
    }
    float4 b0 = *reinterpret_cast<const float4*>(&wB[h * 32 + kg * 4]);
    float4 b1 = *reinterpret_cast<const float4*>(&wB[h * 32 + 16 + kg * 4]);
#pragma unroll
    for (int bt = 0; bt < 4; ++bt)
      qpp[bt] = pack2b(acc[0][bt], b0, acc[1][bt], b1);
  }

  // ---------------- Attention: fully fused per-bt column pipeline ----------------
  const int cls = ((wi == 15) ? 2 : 0) + ((wj == 15) ? 1 : 0);
#pragma unroll
  for (int bt = 0; bt < 4; ++bt) {
    int qtb = bt * 16 + lr;
    const float* rp = wRM + (((size_t)cls * 4 + h) * 64 + qtb) * 64 + kg * 4;
    float4 r4[4];
#pragma unroll
    for (int tt = 0; tt < 4; ++tt)
      r4[tt] = *reinterpret_cast<const float4*>(&rp[tt * 16]);
    f32x4 sc[4] = {};
#pragma unroll
    for (int tt = 0; tt < 4; ++tt)
      sc[tt] = __builtin_amdgcn_mfma_f32_16x16x32_bf16(kfp[tt], qpp[bt], sc[tt], 0, 0, 0);
    float sm = 0.0f;
#pragma unroll
    for (int tt = 0; tt < 4; ++tt) {
#pragma unroll
      for (int i = 0; i < 4; ++i) {
        float e = exp2f(fminf(sc[tt][i] + r4[tt][i], 86.0f));
        sc[tt][i] = e; sm += e;
      }
    }
    bf16x8 p0 = pack2(sc[0], sc[1]);
    bf16x8 p1 = pack2(sc[2], sc[3]);
    f32x4 ob[2] = {};
#pragma unroll
    for (int nt = 0; nt < 2; ++nt) {
      ob[nt] = __builtin_amdgcn_mfma_f32_16x16x32_bf16(vfp[0][nt], p0, ob[nt], 0, 0, 0);
      ob[nt] = __builtin_amdgcn_mfma_f32_16x16x32_bf16(vfp[1][nt], p1, ob[nt], 0, 0, 0);
    }
    sm += __shfl_xor(sm, 16);
    sm += __shfl_xor(sm, 32);
    float iv = 1.0f / sm;
    if (qtb < 49) {
#pragma unroll
      for (int nt = 0; nt < 2; ++nt) {
        ushort4 h4 = { f2bf(ob[nt][0] * iv), f2bf(ob[nt][1] * iv),
                       f2bf(ob[nt][2] * iv), f2bf(ob[nt][3] * iv) };
        *reinterpret_cast<ushort4*>(&lds[OS + qtb * 136 + h * 32 + nt * 16 + kg * 4]) = h4;
      }
    }
  }
  __syncthreads();  // barrier 2

  // ---------------- output projection (swapped) + float4 scatter (per-kk reads) ----------------
  {
    const int c0 = wv * 32;
    const ushort* W = wW + 3 * 16384;
    f32x4 acc[2][4] = {};
#pragma unroll
    for (int kk = 0; kk < 4; ++kk) {
      bf16x8 w0 = *reinterpret_cast<const bf16x8*>(&W[(c0 + lr) * 128 + kk * 32 + kg * 8]);
      bf16x8 w1 = *reinterpret_cast<const bf16x8*>(&W[(c0 + 16 + lr) * 128 + kk * 32 + kg * 8]);
#pragma unroll
      for (int ntk = 0; ntk < 4; ++ntk) {
        int row = (ntk < 3) ? (ntk * 16 + lr) : ((r3 > 48) ? 48 : r3);
        bf16x8 bo = *reinterpret_cast<const bf16x8*>(&lds[OS + row * 136 + kk * 32 + kg * 8]);
        acc[0][ntk] = __builtin_amdgcn_mfma_f32_16x16x32_bf16(w0, bo, acc[0][ntk], 0, 0, 0);
        acc[1][ntk] = __builtin_amdgcn_mfma_f32_16x16x32_bf16(w1, bo, acc[1][ntk], 0, 0, 0);
      }
    }
#pragma unroll
    for (int mt = 0; mt < 2; ++mt) {
      float4 b4 = *reinterpret_cast<const float4*>(&wB[384 + c0 + mt * 16 + kg * 4]);
#pragma unroll
      for (int ntk = 0; ntk < 4; ++ntk) {
        int tok = ntk * 16 + lr;
        if (tok < 49) {
          int r = d7(tok), c = tok - r * 7;
          int gh = wi * 7 + r + SHF; if (gh >= IMG) gh -= IMG;
          int gw = wj * 7 + c + SHF; if (gw >= IMG) gw -= IMG;
          float4 o4 = { acc[mt][ntk][0] + b4.x, acc[mt][ntk][1] + b4.y,
                        acc[mt][ntk][2] + b4.z, acc[mt][ntk][3] + b4.w };
          *reinterpret_cast<float4*>(out + gBase + ((size_t)gh * IMG + gw) * 128 + c0 + mt * 16 + kg * 4) = o4;
        }
      }
    }
  }
}

extern "C" void kernel_launch(void* const* d_in, const int* in_sizes, int n_in,
                              void* d_out, int out_size, void* d_ws, size_t ws_size,
                              hipStream_t stream) {
  const float* X = (const float*)d_in[0];
  const float* Wq = (const float*)d_in[3];
  const float* Wk = (const float*)d_in[4];
  const float* Wv = (const float*)d_in[5];
  const float* Wp = (const float*)d_in[6];
  const float* bq = (const float*)d_in[7];
  const float* bk = (const float*)d_in[8];
  const float* bv = (const float*)d_in[9];
  const float* bp = (const float*)d_in[10];
  const float* tbl = (const float*)d_in[11];

  ushort* wW = (ushort*)d_ws;                             // 4 x [128][128] bf16 = 131072 B
  float* wB = (float*)((char*)d_ws + 131072);             // 4 x [128] f32   = 2048 B
  float* wRM = (float*)((char*)d_ws + 131072 + 2048);     // [4][4][64][64] f32 = 262144 B

  prep_kernel<<<dim3(514), dim3(256), 0, stream>>>(Wq, Wk, Wv, Wp, bq, bk, bv, bp, tbl, wW, wB, wRM);
  swin_kernel<<<dim3(8192), dim3(256), 0, stream>>>(X, wW, wB, wRM, (float*)d_out);
}

// Round 22
// 266.140 us; speedup vs baseline: 1.0565x; 1.0565x over previous
//
#include <hip/hip_runtime.h>

typedef __attribute__((ext_vector_type(8))) __bf16 bf16x8;
typedef __attribute__((ext_vector_type(4))) float f32x4;

#define IMG 112
#define SHF 3

__device__ __forceinline__ ushort f2bf(float f) {
  return __builtin_bit_cast(unsigned short, static_cast<__bf16>(f));
}
__device__ __forceinline__ uint pk2(float lo, float hi) {
  return (uint)f2bf(lo) | ((uint)f2bf(hi) << 16);
}
__device__ __forceinline__ int d7(int n) { return (n * 9363) >> 16; }  // n/7 for n<=63

// Full-K=32 packing of two D-frags (verified R16): k' = 8*kg + j;
// j=0..3 <- d0 rows (kg*4+i), j=4..7 <- d1 rows (16+kg*4+i).
__device__ __forceinline__ bf16x8 pack2(const f32x4 d0, const f32x4 d1) {
  union { uint4 u; bf16x8 v; } r;
  r.u = uint4{ pk2(d0[0], d0[1]), pk2(d0[2], d0[3]),
               pk2(d1[0], d1[1]), pk2(d1[2], d1[3]) };
  return r.v;
}
__device__ __forceinline__ bf16x8 pack2b(const f32x4 d0, const float4 b0,
                                         const f32x4 d1, const float4 b1) {
  union { uint4 u; bf16x8 v; } r;
  r.u = uint4{ pk2(d0[0] + b0.x, d0[1] + b0.y), pk2(d0[2] + b0.z, d0[3] + b0.w),
               pk2(d1[0] + b1.x, d1[1] + b1.y), pk2(d1[2] + b1.z, d1[3] + b1.w) };
  return r.v;
}

// ---------------- prep: bf16 weights (+q scale*log2e fold), biases, log2e-scaled rpb+mask ----
// wRM[cls][h][64 qt][64 kt] = log2e*(rpb + masks); softmax exp done as exp2.
__global__ void prep_kernel(const float* __restrict__ Wq, const float* __restrict__ Wk,
                            const float* __restrict__ Wv, const float* __restrict__ Wp,
                            const float* __restrict__ bq, const float* __restrict__ bk,
                            const float* __restrict__ bv, const float* __restrict__ bp,
                            const float* __restrict__ tbl,
                            ushort* __restrict__ wW, float* __restrict__ wB,
                            float* __restrict__ wRM) {
  int t = blockIdx.x * 256 + threadIdx.x;
  const float LOG2E = 1.4426950408889634f;
  const float SC = 0.17677669529663687f * LOG2E;  // 32^-0.5 * log2(e)
  if (t < 65536) {
    int m = t >> 14, e = t & 16383;
    const float* W = (m == 0) ? Wq : (m == 1) ? Wk : (m == 2) ? Wv : Wp;
    float v = W[e];
    if (m == 0) v *= SC;
    wW[t] = f2bf(v);
  } else if (t < 66048) {
    int t2 = t - 65536;
    int m = t2 >> 7, e = t2 & 127;
    const float* B = (m == 0) ? bq : (m == 1) ? bk : (m == 2) ? bv : bp;
    float v = B[e];
    if (m == 0) v *= SC;
    wB[t2] = v;
  } else if (t < 131584) {
    int t3 = t - 66048;  // [0, 65536)
    int cls = t3 >> 14;
    int r = t3 & 16383;
    int h = r >> 12;
    int rr = r & 4095;
    int qt = rr >> 6, kt = rr & 63;
    float v;
    if (qt >= 49) v = 0.0f;
    else if (kt >= 49) v = -1e30f;
    else {
      int rq = qt / 7, cq = qt % 7, rk = kt / 7, ck = kt % 7;
      v = tbl[((rq - rk + 6) * 13 + (cq - ck + 6)) * 4 + h];
      int eH = (cls >> 1) & 1, eW = cls & 1;
      int ridq = (eH ? (rq < 4 ? 3 : 6) : 0) + (eW ? (cq < 4 ? 1 : 2) : 0);
      int ridk = (eH ? (rk < 4 ? 3 : 6) : 0) + (eW ? (ck < 4 ? 1 : 2) : 0);
      if (ridq != ridk) v -= 100.0f;
    }
    wRM[t3] = v * LOG2E;
  }
}

// LDS (ushort units): x_s [0, 6664) = [49][136];  o_s [6664, 13328) = [49][136].
#define OS 6664

// Block = 256 threads = 4 waves; wave wv = head h, end-to-end in registers.
// Full per-bt fusion (S -> softmax(exp2) -> pack -> PV -> reduce -> o_s, per column)
// at the proven 3-waves/SIMD budget: lowest peak pressure + zero spill.
__global__ __launch_bounds__(256, 3) void swin_kernel(
    const float* __restrict__ X, const ushort* __restrict__ wW,
    const float* __restrict__ wB, const float* __restrict__ wRM,
    float* __restrict__ out) {
  __shared__ ushort lds[13328];
  const int tid = threadIdx.x;
  const int wv = tid >> 6;  // 0..3 = head
  const int lane = tid & 63;
  const int lr = lane & 15;
  const int kg = lane >> 4;

  const int blk = blockIdx.x;
  const int b = blk >> 8;
  const int wid = blk & 255;
  const int wi = wid >> 4, wj = wid & 15;
  const size_t gBase = (size_t)b * (IMG * IMG * 128);
  const int h = wv;
  const int r3 = 48 + lr;

  // ---------------- Phase A: gather rolled window (hoisted chains) ----------------
  {
    float4 va[7]; int rowa[7], q4a[7]; bool ok[7];
#pragma unroll
    for (int i = 0; i < 7; ++i) {
      int idx = tid + i * 256;
      ok[i] = idx < 49 * 32;
      int row = idx >> 5, q4 = idx & 31;
      rowa[i] = row; q4a[i] = q4;
      if (ok[i]) {
        int r = d7(row), c = row - r * 7;
        int gh = wi * 7 + r + SHF; if (gh >= IMG) gh -= IMG;
        int gw = wj * 7 + c + SHF; if (gw >= IMG) gw -= IMG;
        va[i] = reinterpret_cast<const float4*>(X + gBase + ((size_t)gh * IMG + gw) * 128)[q4];
      }
    }
#pragma unroll
    for (int i = 0; i < 7; ++i) {
      if (ok[i]) {
        ushort4 h4 = { f2bf(va[i].x), f2bf(va[i].y), f2bf(va[i].z), f2bf(va[i].w) };
        *reinterpret_cast<ushort4*>(&lds[rowa[i] * 136 + q4a[i] * 4]) = h4;
      }
    }
  }
  __syncthreads();  // barrier 1

  // x-fragment loader (LDS, per-kk, per-tile; tt<3 rows never exceed 47)
  auto ldx = [&](int tt, int kk) -> bf16x8 {
    int row = (tt < 3) ? (tt * 16 + lr) : ((r3 > 48) ? 48 : r3);
    return *reinterpret_cast<const bf16x8*>(&lds[row * 136 + kk * 32 + kg * 8]);
  };

  // ---------------- K projection: D[ch][tok] -> full-K packed A-frags kfp[tt] ----------------
  bf16x8 kfp[4];
  {
    f32x4 acc[2][4] = {};
#pragma unroll
    for (int kk = 0; kk < 4; ++kk) {
      bf16x8 w0 = *reinterpret_cast<const bf16x8*>(&wW[16384 + (h * 32 + lr) * 128 + kk * 32 + kg * 8]);
      bf16x8 w1 = *reinterpret_cast<const bf16x8*>(&wW[16384 + (h * 32 + 16 + lr) * 128 + kk * 32 + kg * 8]);
#pragma unroll
      for (int tt = 0; tt < 4; ++tt) {
        bf16x8 x = ldx(tt, kk);
        acc[0][tt] = __builtin_amdgcn_mfma_f32_16x16x32_bf16(w0, x, acc[0][tt], 0, 0, 0);
        acc[1][tt] = __builtin_amdgcn_mfma_f32_16x16x32_bf16(w1, x, acc[1][tt], 0, 0, 0);
      }
    }
    float4 b0 = *reinterpret_cast<const float4*>(&wB[128 + h * 32 + kg * 4]);
    float4 b1 = *reinterpret_cast<const float4*>(&wB[128 + h * 32 + 16 + kg * 4]);
#pragma unroll
    for (int tt = 0; tt < 4; ++tt)
      kfp[tt] = pack2b(acc[0][tt], b0, acc[1][tt], b1);
  }

  // ---------------- V projection: D[tok][ch] -> full-K packed A-frags vfp[c][nt] ----------------
  bf16x8 vfp[2][2];  // [c tok-pair][nt d-tile]
  {
    f32x4 acc[4][2] = {};
#pragma unroll
    for (int kk = 0; kk < 4; ++kk) {
      bf16x8 w0 = *reinterpret_cast<const bf16x8*>(&wW[32768 + (h * 32 + lr) * 128 + kk * 32 + kg * 8]);
      bf16x8 w1 = *reinterpret_cast<const bf16x8*>(&wW[32768 + (h * 32 + 16 + lr) * 128 + kk * 32 + kg * 8]);
#pragma unroll
      for (int tt = 0; tt < 4; ++tt) {
        bf16x8 x = ldx(tt, kk);
        acc[tt][0] = __builtin_amdgcn_mfma_f32_16x16x32_bf16(x, w0, acc[tt][0], 0, 0, 0);
        acc[tt][1] = __builtin_amdgcn_mfma_f32_16x16x32_bf16(x, w1, acc[tt][1], 0, 0, 0);
      }
    }
    float bv0 = wB[256 + h * 32 + lr];
    float bv1 = wB[256 + h * 32 + 16 + lr];
#pragma unroll
    for (int c = 0; c < 2; ++c) {
      f32x4 t00 = acc[2 * c][0], t10 = acc[2 * c + 1][0];
      f32x4 t01 = acc[2 * c][1], t11 = acc[2 * c + 1][1];
#pragma unroll
      for (int i = 0; i < 4; ++i) { t00[i] += bv0; t10[i] += bv0; t01[i] += bv1; t11[i] += bv1; }
      vfp[c][0] = pack2(t00, t10);
      vfp[c][1] = pack2(t01, t11);
    }
  }

  // ---------------- Q projection: D[ch][qt] -> full-K packed B-frags qpp[bt] ----------------
  bf16x8 qpp[4];
  {
    f32x4 acc[2][4] = {};
#pragma unroll
    for (int kk = 0; kk < 4; ++kk) {
      bf16x8 w0 = *reinterpret_cast<const bf16x8*>(&wW[(h * 32 + lr) * 128 + kk * 32 + kg * 8]);
      bf16x8 w1 = *reinterpret_cast<const bf16x8*>(&wW[(h * 32 + 16 + lr) * 128 + kk * 32 + kg * 8]);
#pragma unroll
      for (int bt = 0; bt < 4; ++bt) {
        bf16x8 x = ldx(bt, kk);
        acc[0][bt] = __builtin_amdgcn_mfma_f32_16x16x32_bf16(w0, x, acc[0][bt], 0, 0, 0);
        acc[1][bt] = __builtin_amdgcn_mfma_f32_16x16x32_bf16(w1, x, acc[1][bt], 0, 0, 0);
      }
    }
    float4 b0 = *reinterpret_cast<const float4*>(&wB[h * 32 + kg * 4]);
    float4 b1 = *reinterpret_cast<const float4*>(&wB[h * 32 + 16 + kg * 4]);
#pragma unroll
    for (int bt = 0; bt < 4; ++bt)
      qpp[bt] = pack2b(acc[0][bt], b0, acc[1][bt], b1);
  }

  // ---------------- Attention: fully fused per-bt column pipeline ----------------
  const int cls = ((wi == 15) ? 2 : 0) + ((wj == 15) ? 1 : 0);
#pragma unroll
  for (int bt = 0; bt < 4; ++bt) {
    int qtb = bt * 16 + lr;
    const float* rp = wRM + (((size_t)cls * 4 + h) * 64 + qtb) * 64 + kg * 4;
    float4 r4[4];
#pragma unroll
    for (int tt = 0; tt < 4; ++tt)
      r4[tt] = *reinterpret_cast<const float4*>(&rp[tt * 16]);
    f32x4 sc[4] = {};
#pragma unroll
    for (int tt = 0; tt < 4; ++tt)
      sc[tt] = __builtin_amdgcn_mfma_f32_16x16x32_bf16(kfp[tt], qpp[bt], sc[tt], 0, 0, 0);
    float sm = 0.0f;
#pragma unroll
    for (int tt = 0; tt < 4; ++tt) {
#pragma unroll
      for (int i = 0; i < 4; ++i) {
        float e = exp2f(fminf(sc[tt][i] + r4[tt][i], 86.0f));
        sc[tt][i] = e; sm += e;
      }
    }
    bf16x8 p0 = pack2(sc[0], sc[1]);
    bf16x8 p1 = pack2(sc[2], sc[3]);
    f32x4 ob[2] = {};
#pragma unroll
    for (int nt = 0; nt < 2; ++nt) {
      ob[nt] = __builtin_amdgcn_mfma_f32_16x16x32_bf16(vfp[0][nt], p0, ob[nt], 0, 0, 0);
      ob[nt] = __builtin_amdgcn_mfma_f32_16x16x32_bf16(vfp[1][nt], p1, ob[nt], 0, 0, 0);
    }
    sm += __shfl_xor(sm, 16);
    sm += __shfl_xor(sm, 32);
    float iv = 1.0f / sm;
    if (qtb < 49) {
#pragma unroll
      for (int nt = 0; nt < 2; ++nt) {
        ushort4 h4 = { f2bf(ob[nt][0] * iv), f2bf(ob[nt][1] * iv),
                       f2bf(ob[nt][2] * iv), f2bf(ob[nt][3] * iv) };
        *reinterpret_cast<ushort4*>(&lds[OS + qtb * 136 + h * 32 + nt * 16 + kg * 4]) = h4;
      }
    }
  }
  __syncthreads();  // barrier 2

  // ---------------- output projection (swapped) + float4 scatter (per-kk reads) ----------------
  {
    const int c0 = wv * 32;
    const ushort* W = wW + 3 * 16384;
    f32x4 acc[2][4] = {};
#pragma unroll
    for (int kk = 0; kk < 4; ++kk) {
      bf16x8 w0 = *reinterpret_cast<const bf16x8*>(&W[(c0 + lr) * 128 + kk * 32 + kg * 8]);
      bf16x8 w1 = *reinterpret_cast<const bf16x8*>(&W[(c0 + 16 + lr) * 128 + kk * 32 + kg * 8]);
#pragma unroll
      for (int ntk = 0; ntk < 4; ++ntk) {
        int row = (ntk < 3) ? (ntk * 16 + lr) : ((r3 > 48) ? 48 : r3);
        bf16x8 bo = *reinterpret_cast<const bf16x8*>(&lds[OS + row * 136 + kk * 32 + kg * 8]);
        acc[0][ntk] = __builtin_amdgcn_mfma_f32_16x16x32_bf16(w0, bo, acc[0][ntk], 0, 0, 0);
        acc[1][ntk] = __builtin_amdgcn_mfma_f32_16x16x32_bf16(w1, bo, acc[1][ntk], 0, 0, 0);
      }
    }
#pragma unroll
    for (int mt = 0; mt < 2; ++mt) {
      float4 b4 = *reinterpret_cast<const float4*>(&wB[384 + c0 + mt * 16 + kg * 4]);
#pragma unroll
      for (int ntk = 0; ntk < 4; ++ntk) {
        int tok = ntk * 16 + lr;
        if (tok < 49) {
          int r = d7(tok), c = tok - r * 7;
          int gh = wi * 7 + r + SHF; if (gh >= IMG) gh -= IMG;
          int gw = wj * 7 + c + SHF; if (gw >= IMG) gw -= IMG;
          float4 o4 = { acc[mt][ntk][0] + b4.x, acc[mt][ntk][1] + b4.y,
                        acc[mt][ntk][2] + b4.z, acc[mt][ntk][3] + b4.w };
          *reinterpret_cast<float4*>(out + gBase + ((size_t)gh * IMG + gw) * 128 + c0 + mt * 16 + kg * 4) = o4;
        }
      }
    }
  }
}

extern "C" void kernel_launch(void* const* d_in, const int* in_sizes, int n_in,
                              void* d_out, int out_size, void* d_ws, size_t ws_size,
                              hipStream_t stream) {
  const float* X = (const float*)d_in[0];
  const float* Wq = (const float*)d_in[3];
  const float* Wk = (const float*)d_in[4];
  const float* Wv = (const float*)d_in[5];
  const float* Wp = (const float*)d_in[6];
  const float* bq = (const float*)d_in[7];
  const float* bk = (const float*)d_in[8];
  const float* bv = (const float*)d_in[9];
  const float* bp = (const float*)d_in[10];
  const float* tbl = (const float*)d_in[11];

  ushort* wW = (ushort*)d_ws;                             // 4 x [128][128] bf16 = 131072 B
  float* wB = (float*)((char*)d_ws + 131072);             // 4 x [128] f32   = 2048 B
  float* wRM = (float*)((char*)d_ws + 131072 + 2048);     // [4][4][64][64] f32 = 262144 B

  prep_kernel<<<dim3(514), dim3(256), 0, stream>>>(Wq, Wk, Wv, Wp, bq, bk, bv, bp, tbl, wW, wB, wRM);
  swin_kernel<<<dim3(8192), dim3(256), 0, stream>>>(X, wW, wB, wRM, (float*)d_out);
}

// Round 23
// 246.327 us; speedup vs baseline: 1.1414x; 1.0804x over previous
//
#include <hip/hip_runtime.h>

typedef __attribute__((ext_vector_type(8))) __bf16 bf16x8;
typedef __attribute__((ext_vector_type(4))) float f32x4;

#define IMG 112
#define SHF 3

__device__ __forceinline__ ushort f2bf(float f) {
  return __builtin_bit_cast(unsigned short, static_cast<__bf16>(f));
}
__device__ __forceinline__ uint pk2(float lo, float hi) {
  return (uint)f2bf(lo) | ((uint)f2bf(hi) << 16);
}
__device__ __forceinline__ int d7(int n) { return (n * 9363) >> 16; }  // n/7 for n<=63

// Full-K=32 packing of two D-frags (verified R16): k' = 8*kg + j;
// j=0..3 <- d0 rows (kg*4+i), j=4..7 <- d1 rows (16+kg*4+i).
__device__ __forceinline__ bf16x8 pack2(const f32x4 d0, const f32x4 d1) {
  union { uint4 u; bf16x8 v; } r;
  r.u = uint4{ pk2(d0[0], d0[1]), pk2(d0[2], d0[3]),
               pk2(d1[0], d1[1]), pk2(d1[2], d1[3]) };
  return r.v;
}
__device__ __forceinline__ bf16x8 pack2b(const f32x4 d0, const float4 b0,
                                         const f32x4 d1, const float4 b1) {
  union { uint4 u; bf16x8 v; } r;
  r.u = uint4{ pk2(d0[0] + b0.x, d0[1] + b0.y), pk2(d0[2] + b0.z, d0[3] + b0.w),
               pk2(d1[0] + b1.x, d1[1] + b1.y), pk2(d1[2] + b1.z, d1[3] + b1.w) };
  return r.v;
}

// ---------------- prep: bf16 weights (+q scale*log2e fold), biases, log2e-scaled rpb+mask ----
// wRM[cls][h][64 qt][64 kt] = log2e*(rpb + masks); softmax exp done as exp2.
__global__ void prep_kernel(const float* __restrict__ Wq, const float* __restrict__ Wk,
                            const float* __restrict__ Wv, const float* __restrict__ Wp,
                            const float* __restrict__ bq, const float* __restrict__ bk,
                            const float* __restrict__ bv, const float* __restrict__ bp,
                            const float* __restrict__ tbl,
                            ushort* __restrict__ wW, float* __restrict__ wB,
                            float* __restrict__ wRM) {
  int t = blockIdx.x * 256 + threadIdx.x;
  const float LOG2E = 1.4426950408889634f;
  const float SC = 0.17677669529663687f * LOG2E;  // 32^-0.5 * log2(e)
  if (t < 65536) {
    int m = t >> 14, e = t & 16383;
    const float* W = (m == 0) ? Wq : (m == 1) ? Wk : (m == 2) ? Wv : Wp;
    float v = W[e];
    if (m == 0) v *= SC;
    wW[t] = f2bf(v);
  } else if (t < 66048) {
    int t2 = t - 65536;
    int m = t2 >> 7, e = t2 & 127;
    const float* B = (m == 0) ? bq : (m == 1) ? bk : (m == 2) ? bv : bp;
    float v = B[e];
    if (m == 0) v *= SC;
    wB[t2] = v;
  } else if (t < 131584) {
    int t3 = t - 66048;  // [0, 65536)
    int cls = t3 >> 14;
    int r = t3 & 16383;
    int h = r >> 12;
    int rr = r & 4095;
    int qt = rr >> 6, kt = rr & 63;
    float v;
    if (qt >= 49) v = 0.0f;
    else if (kt >= 49) v = -1e30f;
    else {
      int rq = qt / 7, cq = qt % 7, rk = kt / 7, ck = kt % 7;
      v = tbl[((rq - rk + 6) * 13 + (cq - ck + 6)) * 4 + h];
      int eH = (cls >> 1) & 1, eW = cls & 1;
      int ridq = (eH ? (rq < 4 ? 3 : 6) : 0) + (eW ? (cq < 4 ? 1 : 2) : 0);
      int ridk = (eH ? (rk < 4 ? 3 : 6) : 0) + (eW ? (ck < 4 ? 1 : 2) : 0);
      if (ridq != ridk) v -= 100.0f;
    }
    wRM[t3] = v * LOG2E;
  }
}

// LDS (ushort units): x_s [0, 6664) = [49][136];  o_s [6664, 13328) = [49][136].
#define OS 6664

// Block = 256 threads = 4 waves; wave wv = head h, end-to-end in registers.
// Register-lean: x frags re-read from LDS per-kk; per-bt fused S->softmax->pack->PV;
// phase-separated normalize + o_s write (best register shape found, R20 champion).
__global__ __launch_bounds__(256, 3) void swin_kernel(
    const float* __restrict__ X, const ushort* __restrict__ wW,
    const float* __restrict__ wB, const float* __restrict__ wRM,
    float* __restrict__ out) {
  __shared__ ushort lds[13328];
  const int tid = threadIdx.x;
  const int wv = tid >> 6;  // 0..3 = head
  const int lane = tid & 63;
  const int lr = lane & 15;
  const int kg = lane >> 4;

  const int blk = blockIdx.x;
  const int b = blk >> 8;
  const int wid = blk & 255;
  const int wi = wid >> 4, wj = wid & 15;
  const size_t gBase = (size_t)b * (IMG * IMG * 128);
  const int h = wv;
  const int r3 = 48 + lr;

  // ---------------- Phase A: gather rolled window (hoisted chains) ----------------
  {
    float4 va[7]; int rowa[7], q4a[7]; bool ok[7];
#pragma unroll
    for (int i = 0; i < 7; ++i) {
      int idx = tid + i * 256;
      ok[i] = idx < 49 * 32;
      int row = idx >> 5, q4 = idx & 31;
      rowa[i] = row; q4a[i] = q4;
      if (ok[i]) {
        int r = d7(row), c = row - r * 7;
        int gh = wi * 7 + r + SHF; if (gh >= IMG) gh -= IMG;
        int gw = wj * 7 + c + SHF; if (gw >= IMG) gw -= IMG;
        va[i] = reinterpret_cast<const float4*>(X + gBase + ((size_t)gh * IMG + gw) * 128)[q4];
      }
    }
#pragma unroll
    for (int i = 0; i < 7; ++i) {
      if (ok[i]) {
        ushort4 h4 = { f2bf(va[i].x), f2bf(va[i].y), f2bf(va[i].z), f2bf(va[i].w) };
        *reinterpret_cast<ushort4*>(&lds[rowa[i] * 136 + q4a[i] * 4]) = h4;
      }
    }
  }
  __syncthreads();  // barrier 1

  // x-fragment loader (LDS, per-kk, per-tile; tt<3 rows never exceed 47)
  auto ldx = [&](int tt, int kk) -> bf16x8 {
    int row = (tt < 3) ? (tt * 16 + lr) : ((r3 > 48) ? 48 : r3);
    return *reinterpret_cast<const bf16x8*>(&lds[row * 136 + kk * 32 + kg * 8]);
  };

  // ---------------- K projection: D[ch][tok] -> full-K packed A-frags kfp[tt] ----------------
  bf16x8 kfp[4];
  {
    f32x4 acc[2][4] = {};
#pragma unroll
    for (int kk = 0; kk < 4; ++kk) {
      bf16x8 w0 = *reinterpret_cast<const bf16x8*>(&wW[16384 + (h * 32 + lr) * 128 + kk * 32 + kg * 8]);
      bf16x8 w1 = *reinterpret_cast<const bf16x8*>(&wW[16384 + (h * 32 + 16 + lr) * 128 + kk * 32 + kg * 8]);
#pragma unroll
      for (int tt = 0; tt < 4; ++tt) {
        bf16x8 x = ldx(tt, kk);
        acc[0][tt] = __builtin_amdgcn_mfma_f32_16x16x32_bf16(w0, x, acc[0][tt], 0, 0, 0);
        acc[1][tt] = __builtin_amdgcn_mfma_f32_16x16x32_bf16(w1, x, acc[1][tt], 0, 0, 0);
      }
    }
    float4 b0 = *reinterpret_cast<const float4*>(&wB[128 + h * 32 + kg * 4]);
    float4 b1 = *reinterpret_cast<const float4*>(&wB[128 + h * 32 + 16 + kg * 4]);
#pragma unroll
    for (int tt = 0; tt < 4; ++tt)
      kfp[tt] = pack2b(acc[0][tt], b0, acc[1][tt], b1);
  }

  // ---------------- V projection: D[tok][ch] -> full-K packed A-frags vfp[c][nt] ----------------
  bf16x8 vfp[2][2];  // [c tok-pair][nt d-tile]
  {
    f32x4 acc[4][2] = {};
#pragma unroll
    for (int kk = 0; kk < 4; ++kk) {
      bf16x8 w0 = *reinterpret_cast<const bf16x8*>(&wW[32768 + (h * 32 + lr) * 128 + kk * 32 + kg * 8]);
      bf16x8 w1 = *reinterpret_cast<const bf16x8*>(&wW[32768 + (h * 32 + 16 + lr) * 128 + kk * 32 + kg * 8]);
#pragma unroll
      for (int tt = 0; tt < 4; ++tt) {
        bf16x8 x = ldx(tt, kk);
        acc[tt][0] = __builtin_amdgcn_mfma_f32_16x16x32_bf16(x, w0, acc[tt][0], 0, 0, 0);
        acc[tt][1] = __builtin_amdgcn_mfma_f32_16x16x32_bf16(x, w1, acc[tt][1], 0, 0, 0);
      }
    }
    float bv0 = wB[256 + h * 32 + lr];
    float bv1 = wB[256 + h * 32 + 16 + lr];
#pragma unroll
    for (int c = 0; c < 2; ++c) {
      f32x4 t00 = acc[2 * c][0], t10 = acc[2 * c + 1][0];
      f32x4 t01 = acc[2 * c][1], t11 = acc[2 * c + 1][1];
#pragma unroll
      for (int i = 0; i < 4; ++i) { t00[i] += bv0; t10[i] += bv0; t01[i] += bv1; t11[i] += bv1; }
      vfp[c][0] = pack2(t00, t10);
      vfp[c][1] = pack2(t01, t11);
    }
  }

  // ---------------- Q projection: D[ch][qt] -> full-K packed B-frags qpp[bt] ----------------
  bf16x8 qpp[4];
  {
    f32x4 acc[2][4] = {};
#pragma unroll
    for (int kk = 0; kk < 4; ++kk) {
      bf16x8 w0 = *reinterpret_cast<const bf16x8*>(&wW[(h * 32 + lr) * 128 + kk * 32 + kg * 8]);
      bf16x8 w1 = *reinterpret_cast<const bf16x8*>(&wW[(h * 32 + 16 + lr) * 128 + kk * 32 + kg * 8]);
#pragma unroll
      for (int bt = 0; bt < 4; ++bt) {
        bf16x8 x = ldx(bt, kk);
        acc[0][bt] = __builtin_amdgcn_mfma_f32_16x16x32_bf16(w0, x, acc[0][bt], 0, 0, 0);
        acc[1][bt] = __builtin_amdgcn_mfma_f32_16x16x32_bf16(w1, x, acc[1][bt], 0, 0, 0);
      }
    }
    float4 b0 = *reinterpret_cast<const float4*>(&wB[h * 32 + kg * 4]);
    float4 b1 = *reinterpret_cast<const float4*>(&wB[h * 32 + 16 + kg * 4]);
#pragma unroll
    for (int bt = 0; bt < 4; ++bt)
      qpp[bt] = pack2b(acc[0][bt], b0, acc[1][bt], b1);
  }

  // ---------------- Attention: per-bt fused S -> softmax(exp2) -> pack -> PV ----------------
  const int cls = ((wi == 15) ? 2 : 0) + ((wj == 15) ? 1 : 0);
  float sum[4];
  f32x4 o[2][4] = {};  // [nt d-tile][bt]
#pragma unroll
  for (int bt = 0; bt < 4; ++bt) {
    int qtb = bt * 16 + lr;
    const float* rp = wRM + (((size_t)cls * 4 + h) * 64 + qtb) * 64 + kg * 4;
    float4 r4[4];
#pragma unroll
    for (int tt = 0; tt < 4; ++tt)
      r4[tt] = *reinterpret_cast<const float4*>(&rp[tt * 16]);
    f32x4 sc[4] = {};
#pragma unroll
    for (int tt = 0; tt < 4; ++tt)
      sc[tt] = __builtin_amdgcn_mfma_f32_16x16x32_bf16(kfp[tt], qpp[bt], sc[tt], 0, 0, 0);
    float sm = 0.0f;
#pragma unroll
    for (int tt = 0; tt < 4; ++tt) {
#pragma unroll
      for (int i = 0; i < 4; ++i) {
        float e = exp2f(fminf(sc[tt][i] + r4[tt][i], 86.0f));
        sc[tt][i] = e; sm += e;
      }
    }
    sum[bt] = sm;
    bf16x8 p0 = pack2(sc[0], sc[1]);
    bf16x8 p1 = pack2(sc[2], sc[3]);
#pragma unroll
    for (int nt = 0; nt < 2; ++nt) {
      o[nt][bt] = __builtin_amdgcn_mfma_f32_16x16x32_bf16(vfp[0][nt], p0, o[nt][bt], 0, 0, 0);
      o[nt][bt] = __builtin_amdgcn_mfma_f32_16x16x32_bf16(vfp[1][nt], p1, o[nt][bt], 0, 0, 0);
    }
  }

  float inv[4];
#pragma unroll
  for (int bt = 0; bt < 4; ++bt) {
    float sm = sum[bt];
    sm += __shfl_xor(sm, 16);
    sm += __shfl_xor(sm, 32);
    inv[bt] = 1.0f / sm;
  }

  // ---------------- O (scaled) -> o_s[tok][ch] ----------------
#pragma unroll
  for (int bt = 0; bt < 4; ++bt) {
    int qtb = bt * 16 + lr;
    if (qtb < 49) {
      float iv = inv[bt];
#pragma unroll
      for (int nt = 0; nt < 2; ++nt) {
        ushort4 h4 = { f2bf(o[nt][bt][0] * iv), f2bf(o[nt][bt][1] * iv),
                       f2bf(o[nt][bt][2] * iv), f2bf(o[nt][bt][3] * iv) };
        *reinterpret_cast<ushort4*>(&lds[OS + qtb * 136 + h * 32 + nt * 16 + kg * 4]) = h4;
      }
    }
  }
  __syncthreads();  // barrier 2

  // ---------------- output projection (swapped) + float4 scatter (per-kk reads) ----------------
  {
    const int c0 = wv * 32;
    const ushort* W = wW + 3 * 16384;
    f32x4 acc[2][4] = {};
#pragma unroll
    for (int kk = 0; kk < 4; ++kk) {
      bf16x8 w0 = *reinterpret_cast<const bf16x8*>(&W[(c0 + lr) * 128 + kk * 32 + kg * 8]);
      bf16x8 w1 = *reinterpret_cast<const bf16x8*>(&W[(c0 + 16 + lr) * 128 + kk * 32 + kg * 8]);
#pragma unroll
      for (int ntk = 0; ntk < 4; ++ntk) {
        int row = (ntk < 3) ? (ntk * 16 + lr) : ((r3 > 48) ? 48 : r3);
        bf16x8 bo = *reinterpret_cast<const bf16x8*>(&lds[OS + row * 136 + kk * 32 + kg * 8]);
        acc[0][ntk] = __builtin_amdgcn_mfma_f32_16x16x32_bf16(w0, bo, acc[0][ntk], 0, 0, 0);
        acc[1][ntk] = __builtin_amdgcn_mfma_f32_16x16x32_bf16(w1, bo, acc[1][ntk], 0, 0, 0);
      }
    }
#pragma unroll
    for (int mt = 0; mt < 2; ++mt) {
      float4 b4 = *reinterpret_cast<const float4*>(&wB[384 + c0 + mt * 16 + kg * 4]);
#pragma unroll
      for (int ntk = 0; ntk < 4; ++ntk) {
        int tok = ntk * 16 + lr;
        if (tok < 49) {
          int r = d7(tok), c = tok - r * 7;
          int gh = wi * 7 + r + SHF; if (gh >= IMG) gh -= IMG;
          int gw = wj * 7 + c + SHF; if (gw >= IMG) gw -= IMG;
          float4 o4 = { acc[mt][ntk][0] + b4.x, acc[mt][ntk][1] + b4.y,
                        acc[mt][ntk][2] + b4.z, acc[mt][ntk][3] + b4.w };
          *reinterpret_cast<float4*>(out + gBase + ((size_t)gh * IMG + gw) * 128 + c0 + mt * 16 + kg * 4) = o4;
        }
      }
    }
  }
}

extern "C" void kernel_launch(void* const* d_in, const int* in_sizes, int n_in,
                              void* d_out, int out_size, void* d_ws, size_t ws_size,
                              hipStream_t stream) {
  const float* X = (const float*)d_in[0];
  const float* Wq = (const float*)d_in[3];
  const float* Wk = (const float*)d_in[4];
  const float* Wv = (const float*)d_in[5];
  const float* Wp = (const float*)d_in[6];
  const float* bq = (const float*)d_in[7];
  const float* bk = (const float*)d_in[8];
  const float* bv = (const float*)d_in[9];
  const float* bp = (const float*)d_in[10];
  const float* tbl = (const float*)d_in[11];

  ushort* wW = (ushort*)d_ws;                             // 4 x [128][128] bf16 = 131072 B
  float* wB = (float*)((char*)d_ws + 131072);             // 4 x [128] f32   = 2048 B
  float* wRM = (float*)((char*)d_ws + 131072 + 2048);     // [4][4][64][64] f32 = 262144 B

  prep_kernel<<<dim3(514), dim3(256), 0, stream>>>(Wq, Wk, Wv, Wp, bq, bk, bv, bp, tbl, wW, wB, wRM);
  swin_kernel<<<dim3(8192), dim3(256), 0, stream>>>(X, wW, wB, wRM, (float*)d_out);
}